// Round 6
// baseline (169.901 us; speedup 1.0000x reference)
//
#include <hip/hip_runtime.h>
#include <hip/hip_fp16.h>

#define NQ 4096
#define NH 8
#define ND 32
#define NK 30720   // 16384+8192+4096+2048
#define LDSS 33    // padded LDS row stride (conflict-free)

// ---- Pre-pass: value fp32 -> fp16 into workspace (halves gather traffic) ----
__global__ __launch_bounds__(256) void cvt_kernel(const float* __restrict__ v,
                                                  uint4* __restrict__ o, int n8) {
    int i = blockIdx.x * blockDim.x + threadIdx.x;
    const float4* __restrict__ v4 = (const float4*)v;
    for (; i < n8; i += gridDim.x * blockDim.x) {
        const float4 f0 = v4[2 * i];
        const float4 f1 = v4[2 * i + 1];
        __half2 h0 = __floats2half2_rn(f0.x, f0.y);
        __half2 h1 = __floats2half2_rn(f0.z, f0.w);
        __half2 h2 = __floats2half2_rn(f1.x, f1.y);
        __half2 h3 = __floats2half2_rn(f1.z, f1.w);
        uint4 u;
        u.x = *reinterpret_cast<unsigned*>(&h0);
        u.y = *reinterpret_cast<unsigned*>(&h1);
        u.z = *reinterpret_cast<unsigned*>(&h2);
        u.w = *reinterpret_cast<unsigned*>(&h3);
        o[i] = u;
    }
}

__device__ __forceinline__ void load4(const uint2* __restrict__ vb2,
                                      const uint2* s_d, int jj, int cb,
                                      unsigned lane, unsigned* w,
                                      uint2* ra, uint2* rb) {
    #pragma unroll
    for (int u = 0; u < 4; ++u) {
        const uint2 d = s_d[(jj + u) * LDSS + cb];
        w[u]  = d.y;
        ra[u] = vb2[((d.x & 0xffffu) << 6) + lane];
        rb[u] = vb2[((d.x >> 16) << 6) + lane];
    }
}

__device__ __forceinline__ void consume4(const unsigned* w, const uint2* ra,
                                         const uint2* rb, float4& acc) {
    #pragma unroll
    for (int u = 0; u < 4; ++u) {
        const __half2 wh = *reinterpret_cast<const __half2*>(&w[u]);
        const float w1 = __low2float(wh);
        const float w2 = __high2float(wh);
        const float2 a0 = __half22float2(*(const __half2*)&ra[u].x);
        const float2 a1 = __half22float2(*(const __half2*)&ra[u].y);
        const float2 c0 = __half22float2(*(const __half2*)&rb[u].x);
        const float2 c1 = __half22float2(*(const __half2*)&rb[u].y);
        acc.x += w1 * a0.x + w2 * c0.x;
        acc.y += w1 * a0.y + w2 * c0.y;
        acc.z += w1 * a1.x + w2 * c1.x;
        acc.w += w1 * a1.y + w2 * c1.y;
    }
}

// Work partition: 8 groups = (batch, h-half), one per XCD. Per-XCD distinct-line
// gather footprint = 3.93 MB fp16 (~L2-resident). Block: 8 queries x 4 heads.
// Phase 1: 1024 packed descriptors {k1|k2<<16, half2(w1,w2)} into LDS.
// Phase 2: depth-4 double-buffered gather pipeline (safe now: footprint is
// capacity-bounded, so deeper issue cannot blow the L2 set like R3/R4 did).
template <bool FP16>
__global__ __launch_bounds__(256, 8) void spd_kernel(
    const float* __restrict__ value,   // (bs, NK, H, D) fp32
    const __half* __restrict__ vh,     // same, fp16 (workspace), if FP16
    const float* __restrict__ loc,     // (bs, NQ, H, LV, P, 1)
    const float* __restrict__ wts,     // (bs, NQ, H, LV, P)
    float* __restrict__ out)           // (bs, NQ, H*D)
{
    const int tid = threadIdx.x;
    const int g  = blockIdx.x & 7;     // XCD id = group = b*2 + hh
    const int w  = blockIdx.x >> 3;    // [0,512) within group
    const int b  = g >> 1;
    const int hh = g & 1;              // which half of the 8 heads
    const int q0 = w << 3;             // first of 8 queries

    __shared__ uint2 s_d[32 * LDSS];   // [row=l*8+p][col=q*4+h4]

    // ---- Phase 1: descriptors for 8 queries x 4 heads x 32 taps ----
    const size_t base = ((size_t)(b * NQ + q0) * 8 + hh * 4) * 32;
    #pragma unroll
    for (int e = 0; e < 4; ++e) {
        const int ent = (e << 8) | tid;    // q(3b)|h4(2b)|l(2b)|p(3b)
        const size_t gidx = base + (size_t)(ent >> 7) * 256 + (ent & 127);
        const float x_loc = loc[gidx];
        const float wq    = wts[gidx];

        const int l   = (ent >> 3) & 3;
        const int L   = 16384 >> l;
        const int off = 32768 - (32768 >> l); // 0,16384,24576,28672

        const float x  = x_loc * (float)L - 1.0f;
        const float xf = floorf(x);
        const float lx = x - xf;
        const float hx = 1.0f - lx;
        const int   xl = (int)xf;
        const int   xh = xl + 1;

        const bool ok1 = (xl >= 0) && (xl < L);
        const bool ok2 = (xh >= 0) && (xh < L);
        int c1 = xl < 0 ? 0 : (xl > L - 1 ? L - 1 : xl);
        int c2 = xh < 0 ? 0 : (xh > L - 1 ? L - 1 : xh);
        const float w1 = ok1 ? wq * hx : 0.0f;
        const float w2 = ok2 ? wq * lx : 0.0f;

        const int li = (ent & 31) * LDSS + (ent >> 5);  // row=lp, col=q*4+h4
        __half2 wh = __floats2half2_rn(w1, w2);
        uint2 d;
        d.x = (unsigned)(off + c1) | ((unsigned)(off + c2) << 16);
        d.y = *reinterpret_cast<unsigned*>(&wh);
        s_d[li] = d;
    }
    __syncthreads();

    // ---- Phase 2: pipelined gather + accumulate ----
    const int qi = tid >> 5;                 // query within block [0,8)
    const int cb = tid >> 3;                 // LDS col = q*4+h4 [0,32)
    const int h  = (hh << 2) | ((tid >> 3) & 3);
    const int d4 = tid & 7;
    const unsigned lane = (unsigned)((h << 3) | d4);  // slice within key row

    float4 acc = make_float4(0.f, 0.f, 0.f, 0.f);

    if (FP16) {
        const uint2* __restrict__ vb2 =
            (const uint2*)(vh) + (size_t)b * (NK * 64);   // 64 uint2 per key

        unsigned wA[4], wB[4];
        uint2 aA[4], bA[4], aB[4], bB[4];

        load4(vb2, s_d, 0, cb, lane, wA, aA, bA);
        load4(vb2, s_d, 4, cb, lane, wB, aB, bB);
        #pragma unroll
        for (int jj = 8; jj < 32; jj += 8) {
            consume4(wA, aA, bA, acc);
            load4(vb2, s_d, jj, cb, lane, wA, aA, bA);
            consume4(wB, aB, bB, acc);
            load4(vb2, s_d, jj + 4, cb, lane, wB, aB, bB);
        }
        consume4(wA, aA, bA, acc);
        consume4(wB, aB, bB, acc);
    } else {
        const float4* __restrict__ vb4 =
            (const float4*)(value) + (size_t)b * (NK * 64); // 64 float4 per key
        #pragma unroll 16
        for (int j = 0; j < 32; ++j) {
            const uint2 d = s_d[j * LDSS + cb];
            const __half2 wh = *reinterpret_cast<const __half2*>(&d.y);
            const float w1 = __low2float(wh);
            const float w2 = __high2float(wh);
            const float4 a = vb4[(size_t)((d.x & 0xffffu) << 6) + lane];
            const float4 c = vb4[(size_t)((d.x >> 16) << 6) + lane];
            acc.x += w1 * a.x + w2 * c.x;
            acc.y += w1 * a.y + w2 * c.y;
            acc.z += w1 * a.z + w2 * c.z;
            acc.w += w1 * a.w + w2 * c.w;
        }
    }

    float4* __restrict__ o4 = (float4*)out;
    o4[(size_t)(b * NQ + q0 + qi) * 64 + lane] = acc;
}

extern "C" void kernel_launch(void* const* d_in, const int* in_sizes, int n_in,
                              void* d_out, int out_size, void* d_ws, size_t ws_size,
                              hipStream_t stream) {
    const float* value = (const float*)d_in[0];
    const float* loc   = (const float*)d_in[1];
    const float* wts   = (const float*)d_in[2];
    float* out = (float*)d_out;

    const int bs = 4;
    const int blocks = 8 * (NQ / 8);  // 8 groups x 512 = 4096
    const size_t need = (size_t)bs * NK * NH * ND * sizeof(__half);  // ~63 MB

    if (ws_size >= need) {
        const int n8 = bs * NK * NH * ND / 8;  // 8 floats per thread-iter
        cvt_kernel<<<2048, 256, 0, stream>>>(value, (uint4*)d_ws, n8);
        spd_kernel<true><<<blocks, 256, 0, stream>>>(value, (const __half*)d_ws,
                                                     loc, wts, out);
    } else {
        spd_kernel<false><<<blocks, 256, 0, stream>>>(value, nullptr,
                                                      loc, wts, out);
    }
}

// Round 7
// 84.055 us; speedup vs baseline: 2.0213x; 2.0213x over previous
//
#include <hip/hip_runtime.h>
#include <hip/hip_fp16.h>

#define NQ 4096
#define NH 8
#define ND 32
#define NK 30720   // 16384+8192+4096+2048
#define LDSS 65    // padded LDS row stride (conflict-free)

// ---- Pre-pass: value fp32 -> fp16 into workspace (halves gather traffic) ----
__global__ __launch_bounds__(256) void cvt_kernel(const float* __restrict__ v,
                                                  uint4* __restrict__ o, int n8) {
    int i = blockIdx.x * blockDim.x + threadIdx.x;
    const float4* __restrict__ v4 = (const float4*)v;
    for (; i < n8; i += gridDim.x * blockDim.x) {
        const float4 f0 = v4[2 * i];
        const float4 f1 = v4[2 * i + 1];
        __half2 h0 = __floats2half2_rn(f0.x, f0.y);
        __half2 h1 = __floats2half2_rn(f0.z, f0.w);
        __half2 h2 = __floats2half2_rn(f1.x, f1.y);
        __half2 h3 = __floats2half2_rn(f1.z, f1.w);
        uint4 u;
        u.x = *reinterpret_cast<unsigned*>(&h0);
        u.y = *reinterpret_cast<unsigned*>(&h1);
        u.z = *reinterpret_cast<unsigned*>(&h2);
        u.w = *reinterpret_cast<unsigned*>(&h3);
        o[i] = u;
    }
}

// Work partition (R5 winner): 8 groups = (batch, h-half), one per XCD; per-XCD
// distinct-line gather footprint 3.93 MB fp16 (~L2-resident).
// Block: 16 queries x 4 heads. Thread = (q, h4, d2) loads uint4 (8 halves) per
// key -> half the load instructions of R5 for the same address stream.
// Phase 1: 2048 packed descriptors {k1|k2<<16, half2(w1,w2)} into LDS.
// Phase 2: plain load-and-consume loop (every explicit-burst variant lost).
template <bool FP16>
__global__ __launch_bounds__(256, 6) void spd_kernel(
    const float* __restrict__ value,   // (bs, NK, H, D) fp32
    const __half* __restrict__ vh,     // same, fp16 (workspace), if FP16
    const float* __restrict__ loc,     // (bs, NQ, H, LV, P, 1)
    const float* __restrict__ wts,     // (bs, NQ, H, LV, P)
    float* __restrict__ out)           // (bs, NQ, H*D)
{
    const int tid = threadIdx.x;
    const int g  = blockIdx.x & 7;     // XCD id = group = b*2 + hh
    const int w  = blockIdx.x >> 3;    // [0,256) within group
    const int b  = g >> 1;
    const int hh = g & 1;              // which half of the 8 heads
    const int q0 = w << 4;             // first of 16 queries

    __shared__ uint2 s_d[32 * LDSS];   // [row=l*8+p][col=q*4+h4]

    // ---- Phase 1: descriptors for 16 queries x 4 heads x 32 taps ----
    const size_t base = ((size_t)(b * NQ + q0) * 8 + hh * 4) * 32;
    #pragma unroll
    for (int e = 0; e < 8; ++e) {
        const int ent = (e << 8) | tid;    // q(4b)|h4(2b)|l(2b)|p(3b)
        const size_t gidx = base + (size_t)(ent >> 7) * 256 + (ent & 127);
        const float x_loc = loc[gidx];
        const float wq    = wts[gidx];

        const int l   = (ent >> 3) & 3;
        const int L   = 16384 >> l;
        const int off = 32768 - (32768 >> l); // 0,16384,24576,28672

        const float x  = x_loc * (float)L - 1.0f;
        const float xf = floorf(x);
        const float lx = x - xf;
        const float hx = 1.0f - lx;
        const int   xl = (int)xf;
        const int   xh = xl + 1;

        const bool ok1 = (xl >= 0) && (xl < L);
        const bool ok2 = (xh >= 0) && (xh < L);
        int c1 = xl < 0 ? 0 : (xl > L - 1 ? L - 1 : xl);
        int c2 = xh < 0 ? 0 : (xh > L - 1 ? L - 1 : xh);
        const float w1 = ok1 ? wq * hx : 0.0f;
        const float w2 = ok2 ? wq * lx : 0.0f;

        const int li = (ent & 31) * LDSS + (ent >> 5);  // row=lp, col=q*4+h4
        __half2 wh = __floats2half2_rn(w1, w2);
        uint2 d;
        d.x = (unsigned)(off + c1) | ((unsigned)(off + c2) << 16);
        d.y = *reinterpret_cast<unsigned*>(&wh);
        s_d[li] = d;
    }
    __syncthreads();

    // ---- Phase 2: gather + accumulate ----
    const int qi = tid >> 4;                 // query within block [0,16)
    const int cb = tid >> 2;                 // LDS col = q*4+h4 [0,64)
    const int h4 = (tid >> 2) & 3;
    const int d2 = tid & 3;                  // uint4 slice (8 halves) of D=32
    const int h  = (hh << 2) | h4;

    float acc[8] = {0.f, 0.f, 0.f, 0.f, 0.f, 0.f, 0.f, 0.f};

    if (FP16) {
        const uint4* __restrict__ vbu =
            (const uint4*)(vh) + (size_t)b * (NK * 32);   // 32 uint4 per key
        const unsigned lane4 = (unsigned)((h << 2) | d2); // [0,32)
        #pragma unroll 8
        for (int j = 0; j < 32; ++j) {
            const uint2 d = s_d[j * LDSS + cb];
            const __half2 wh = *reinterpret_cast<const __half2*>(&d.y);
            const float w1 = __low2float(wh);
            const float w2 = __high2float(wh);
            const uint4 r1 = vbu[((d.x & 0xffffu) << 5) + lane4];
            const uint4 r2 = vbu[((d.x >> 16) << 5) + lane4];
            const float2 a0 = __half22float2(*(const __half2*)&r1.x);
            const float2 a1 = __half22float2(*(const __half2*)&r1.y);
            const float2 a2 = __half22float2(*(const __half2*)&r1.z);
            const float2 a3 = __half22float2(*(const __half2*)&r1.w);
            const float2 c0 = __half22float2(*(const __half2*)&r2.x);
            const float2 c1 = __half22float2(*(const __half2*)&r2.y);
            const float2 c2 = __half22float2(*(const __half2*)&r2.z);
            const float2 c3 = __half22float2(*(const __half2*)&r2.w);
            acc[0] += w1 * a0.x + w2 * c0.x;
            acc[1] += w1 * a0.y + w2 * c0.y;
            acc[2] += w1 * a1.x + w2 * c1.x;
            acc[3] += w1 * a1.y + w2 * c1.y;
            acc[4] += w1 * a2.x + w2 * c2.x;
            acc[5] += w1 * a2.y + w2 * c2.y;
            acc[6] += w1 * a3.x + w2 * c3.x;
            acc[7] += w1 * a3.y + w2 * c3.y;
        }
    } else {
        const float4* __restrict__ vb4 =
            (const float4*)(value) + (size_t)b * (NK * 64); // 64 float4 per key
        const unsigned lf = (unsigned)((h << 3) | (d2 << 1));
        #pragma unroll 8
        for (int j = 0; j < 32; ++j) {
            const uint2 d = s_d[j * LDSS + cb];
            const __half2 wh = *reinterpret_cast<const __half2*>(&d.y);
            const float w1 = __low2float(wh);
            const float w2 = __high2float(wh);
            const unsigned k1 = (d.x & 0xffffu) << 6;
            const unsigned k2 = (d.x >> 16) << 6;
            const float4 a0 = vb4[k1 + lf];
            const float4 a1 = vb4[k1 + lf + 1];
            const float4 c0 = vb4[k2 + lf];
            const float4 c1 = vb4[k2 + lf + 1];
            acc[0] += w1 * a0.x + w2 * c0.x;
            acc[1] += w1 * a0.y + w2 * c0.y;
            acc[2] += w1 * a0.z + w2 * c0.z;
            acc[3] += w1 * a0.w + w2 * c0.w;
            acc[4] += w1 * a1.x + w2 * c1.x;
            acc[5] += w1 * a1.y + w2 * c1.y;
            acc[6] += w1 * a1.z + w2 * c1.z;
            acc[7] += w1 * a1.w + w2 * c1.w;
        }
    }

    float4* __restrict__ o4 = (float4*)out;
    const size_t orow = (size_t)(b * NQ + q0 + qi) * 64;
    const unsigned oc = (unsigned)((h << 3) | (d2 << 1));
    o4[orow + oc]     = make_float4(acc[0], acc[1], acc[2], acc[3]);
    o4[orow + oc + 1] = make_float4(acc[4], acc[5], acc[6], acc[7]);
}

extern "C" void kernel_launch(void* const* d_in, const int* in_sizes, int n_in,
                              void* d_out, int out_size, void* d_ws, size_t ws_size,
                              hipStream_t stream) {
    const float* value = (const float*)d_in[0];
    const float* loc   = (const float*)d_in[1];
    const float* wts   = (const float*)d_in[2];
    float* out = (float*)d_out;

    const int bs = 4;
    const int blocks = 8 * (NQ / 16);  // 8 groups x 256 = 2048
    const size_t need = (size_t)bs * NK * NH * ND * sizeof(__half);  // ~63 MB

    if (ws_size >= need) {
        const int n8 = bs * NK * NH * ND / 8;  // 8 floats per thread-iter
        cvt_kernel<<<2048, 256, 0, stream>>>(value, (uint4*)d_ws, n8);
        spd_kernel<true><<<blocks, 256, 0, stream>>>(value, (const __half*)d_ws,
                                                     loc, wts, out);
    } else {
        spd_kernel<false><<<blocks, 256, 0, stream>>>(value, nullptr,
                                                      loc, wts, out);
    }
}